// Round 11
// baseline (346.329 us; speedup 1.0000x reference)
//
#include <hip/hip_runtime.h>
#include <cstdint>
#include <cstddef>

// ---------------------------------------------------------------------------
// Problem constants (LEVEL=16, LENGTH=64, TOPK=2, SIZE=512, BATCH=32)
// Cheap path: f16 MFMA scores; rows with cheap top-2/3 gaps < DELTA=0.25 get
// exact f32 refinement over candidates {z: cheap[z] >= cheap_top2 - DELTA}.
//
// Ledger (stable r13-r16): total = poison 72 + rest 152 + K1 + conv.
//   r13: K1=91 conv=0  -> 315 (session best)
//   r16: K1=73 conv=44 -> 342 (K1 best-ever via all-DMA contiguous rows +
//        barrier-free compute + B direct from packed P, FETCH 62MB as
//        predicted; but conv_h costs more than K1's saving)
// Ten structural rewrites put a SEPARATE K1's floor at ~73us (3.5x its
// 20us memory roofline, all pipes idle).
// r18: delete K1 as a kernel. K2 only consumes T at its 32 rcell rows ->
// compute them inside K2: stage 32 rh rows (contiguous-1KB GLD16 from
// CH16, r16-proven), run the IDENTICAL r16 MFMA schedule (B direct from
// packed P, XOR-swizzled af), write the 32x512 T-slice to LDS f16
// (bit-identical to T16: same MFMA order + f16 cvt), then the UNCHANGED
// dot/topk/ballot code reads T from LDS. Deletes the K1 dispatch, T16's
// 59MB write + 59MB read, and K1 drain tails. MFMA total 0.85x.
// ---------------------------------------------------------------------------
#define B_DIM   32
#define L_DIM   48
#define NCELLS  904
#define SZ      512
#define NEGF    (-1e8f)
#define DELTA   0.25f
#define MAXC    32          // max candidates per row kept (z-ascending)

// d_out layout (f32), outputs concatenated flat in return order
#define OFF_S   1572864
#define OFF_N   1575936
#define OFF_L   1579008
#define OFF_R   1582080

typedef _Float16  f16x8 __attribute__((ext_vector_type(8)));
typedef float     f32x4 __attribute__((ext_vector_type(4)));

static __device__ __forceinline__ uint16_t f2bf(float f) {
    uint32_t u = __builtin_bit_cast(uint32_t, f);
    u += 0x7fffu + ((u >> 16) & 1u);
    return (uint16_t)(u >> 16);
}

#define GLD16(gp, lp) __builtin_amdgcn_global_load_lds(                        \
        (__attribute__((address_space(1))) void*)(gp),                         \
        (__attribute__((address_space(3))) void*)(lp), 16, 0, 0)

static __device__ __forceinline__ int level_off(int n) {
    return n * 64 - (n * (n - 1)) / 2;
}

// ---------------------------------------------------------------------------
// P0: pack mat into fragment-chunk order, f16(64*mat).
// Chunk c = ksub*32 + q (ksub=k/32 in 0..15, q=n/16 in 0..31), 1KB each:
//   P[c*512 + lane*8 + j] = f16(64 * mat[16q + (lane&15)][32*ksub + (lane>>4)*8 + j])
// A wave reading P + c*512 + lane*8 gets fragment (q, ksub) lane-linear as
// one contiguous, fully-coalesced 1KB transaction.
// ---------------------------------------------------------------------------
__global__ __launch_bounds__(256)
void prep_mat(const float* __restrict__ mat, _Float16* __restrict__ P)
{
    const int tg   = blockIdx.x * 256 + threadIdx.x;   // 0..32767
    const int c    = tg >> 6, lane = tg & 63;
    const int srow = 16 * (c & 31) + (lane & 15);
    const int scol = 32 * (c >> 5) + (lane >> 4) * 8;
    const float4 a = *(const float4*)(mat + (size_t)srow * 512 + scol);
    const float4 b = *(const float4*)(mat + (size_t)srow * 512 + scol + 4);
    f16x8 w;
    w[0]=(_Float16)(a.x*64.f); w[1]=(_Float16)(a.y*64.f);
    w[2]=(_Float16)(a.z*64.f); w[3]=(_Float16)(a.w*64.f);
    w[4]=(_Float16)(b.x*64.f); w[5]=(_Float16)(b.y*64.f);
    w[6]=(_Float16)(b.z*64.f); w[7]=(_Float16)(b.w*64.f);
    *(f16x8*)(P + (size_t)tg * 8) = w;
}

// ---------------------------------------------------------------------------
// P1: CH16 = f16(16*chart_h), row-major [57856][512]. Pure streaming pass,
// 64B in / 32B out per thread, perfectly coalesced.
// ---------------------------------------------------------------------------
__global__ __launch_bounds__(256)
void conv_h(const float* __restrict__ x, _Float16* __restrict__ y)
{
    const size_t i = ((size_t)blockIdx.x * 256 + threadIdx.x) * 16;
#pragma unroll
    for (int h = 0; h < 2; ++h) {
        const float4 a = *(const float4*)(x + i + h * 8);
        const float4 b = *(const float4*)(x + i + h * 8 + 4);
        f16x8 w;
        w[0]=(_Float16)(a.x*16.f); w[1]=(_Float16)(a.y*16.f);
        w[2]=(_Float16)(a.z*16.f); w[3]=(_Float16)(a.w*16.f);
        w[4]=(_Float16)(b.x*16.f); w[5]=(_Float16)(b.y*16.f);
        w[6]=(_Float16)(b.z*16.f); w[7]=(_Float16)(b.w*16.f);
        *(f16x8*)(y + i + h * 8) = w;
    }
}

// ---------------------------------------------------------------------------
// shared epilogue helpers
// ---------------------------------------------------------------------------
static __device__ __forceinline__ void emit_outputs(
    int row, int i1, int i2, float v1, float v2, float* out)
{
    out[OFF_S + row * 2 + 0] = v1;
    out[OFF_S + row * 2 + 1] = v2;
    out[OFF_N + row * 2 + 0] = (float)(i1 >> 2);
    out[OFF_N + row * 2 + 1] = (float)(i2 >> 2);
    out[OFF_L + row * 2 + 0] = (float)((i1 >> 1) & 1);
    out[OFF_L + row * 2 + 1] = (float)((i2 >> 1) & 1);
    out[OFF_R + row * 2 + 0] = (float)(i1 & 1);
    out[OFF_R + row * 2 + 1] = (float)(i2 & 1);
}

static __device__ __forceinline__ void gather_x(
    int row, int pos, int b, const int* top_z,
    const float* __restrict__ chart_h, uint16_t* __restrict__ X, int tid)
{
#pragma unroll
    for (int kq = 0; kq < 2; ++kq) {
        const int z = top_z[kq];
        const int n = z >> 2, lk = (z >> 1) & 1, rk = z & 1;
        const int lcell = level_off(n) + pos;
        const int rcell = level_off(15 - n) + pos + n + 1;
        const float* srcl = chart_h + ((size_t)(lk * B_DIM + b) * NCELLS + lcell) * SZ;
        const float* srcr = chart_h + ((size_t)(rk * B_DIM + b) * NCELLS + rcell) * SZ;
        uint16_t* dst = X + ((size_t)row * 2 + kq) * 1024;
        const int e = tid * 2;
        const float2 a = *(const float2*)(srcl + e);
        const float2 c = *(const float2*)(srcr + e);
        *(uint32_t*)(dst + e)       = (uint32_t)f2bf(a.x) | ((uint32_t)f2bf(a.y) << 16);
        *(uint32_t*)(dst + 512 + e) = (uint32_t)f2bf(c.x) | ((uint32_t)f2bf(c.y) << 16);
    }
}

// ---------------------------------------------------------------------------
// K2': FUSED per-(b,pos) kernel. Grid 1536, 4 waves.
// Phase A (stage): 32 rh rows (r = k*16+n -> rcell) via contiguous-1KB
//   GLD16 from CH16, XOR-unit source swizzle (r16-verified), into Arh 32KB.
// Phase B (MFMA): T-slice[32][512] = Arh @ P^T. Wave w owns cols 128w..+128:
//   acc[2][8]; per w16: 2 swizzled af LDS reads + 8 bf 1KB loads direct
//   from packed P (L2) + 16 MFMA. Identical schedule/order to r16's K1.
// Phase C: Ts[32][512] f16 = cvt(acc)  (bit-identical to old T16 values).
// Phase D (dot/topk): current K2 code verbatim, t0/t1 from Ts LDS,
//   lh from CH16 global (1KB coalesced rows), inv = 1/16384.
// ---------------------------------------------------------------------------
__global__ __launch_bounds__(256, 2)
void score_fused(const float* __restrict__ chart_h,   // f32 (gather_x only)
                 const _Float16* __restrict__ CH16,   // f16(16*chart_h)
                 const _Float16* __restrict__ P,      // packed mat16
                 const float* __restrict__ chart_s,
                 uint32_t* __restrict__ items,
                 int* __restrict__ rowbase,
                 int* __restrict__ counter,
                 int* __restrict__ flags,
                 uint16_t* __restrict__ X,
                 float* __restrict__ out)
{
    __shared__ _Float16 Arh[32 * 512];   // 32 KB, unit-swizzled
    __shared__ _Float16 Ts[32 * 512];    // 32 KB, linear (reads lane-linear)
    __shared__ float s_sh[64];
    __shared__ int top_z[2];
    __shared__ int flag_sh;

    const int row = blockIdx.x;
    const int b   = row / L_DIM;
    const int pos = row % L_DIM;
    const int t = threadIdx.x;
    const int wave = t >> 6, lane = t & 63;
    const int col_l = lane & 15, quad = lane >> 4;

    // ---- Phase A: stage 32 rh rows (row r = k*16+n) ----
#pragma unroll
    for (int i = 0; i < 8; ++i) {
        const int r = wave * 8 + i;
        const int k = r >> 4, n = r & 15;
        const int rcell = level_off(15 - n) + pos + n + 1;
        const size_t grow = (size_t)(k * B_DIM + b) * NCELLS + rcell;
        GLD16(CH16 + grow * 512 + ((lane ^ (r & 7)) * 8),
              (char*)Arh + r * 1024);
    }
    __syncthreads();                     // drain DMA

    // ---- Phase B: MFMA (r16 schedule; wave owns cols wave*128..+128) ----
    f32x4 acc[2][8];
#pragma unroll
    for (int i = 0; i < 2; ++i)
#pragma unroll
        for (int j = 0; j < 8; ++j) acc[i][j] = (f32x4){0.f, 0.f, 0.f, 0.f};

#pragma unroll 4
    for (int w16 = 0; w16 < 16; ++w16) {
        f16x8 af[2];
#pragma unroll
        for (int mi = 0; mi < 2; ++mi) {
            const int r = mi * 16 + col_l;
            const int u = w16 * 4 + quad;
            af[mi] = *(const f16x8*)&Arh[r * 512 + (u ^ (r & 7)) * 8];
        }
#pragma unroll
        for (int ni = 0; ni < 8; ++ni) {
            const int c = w16 * 32 + wave * 8 + ni;
            const f16x8 bf = *(const f16x8*)(P + (size_t)c * 512 + lane * 8);
#pragma unroll
            for (int mi = 0; mi < 2; ++mi)
                acc[mi][ni] = __builtin_amdgcn_mfma_f32_16x16x32_f16(
                    af[mi], bf, acc[mi][ni], 0, 0, 0);
        }
    }

    // ---- Phase C: Ts = f16(acc); C layout col=lane&15, row=quad*4+reg ----
#pragma unroll
    for (int mi = 0; mi < 2; ++mi)
#pragma unroll
        for (int ni = 0; ni < 8; ++ni)
#pragma unroll
            for (int rr = 0; rr < 4; ++rr)
                Ts[(mi * 16 + quad * 4 + rr) * 512 + wave * 128 + ni * 16 + col_l]
                    = (_Float16)acc[mi][ni][rr];
    __syncthreads();                     // Ts visible to all waves

    // ---- Phase D: dot + topk (current K2 verbatim; T from Ts LDS) ----
#pragma unroll
    for (int ni = 0; ni < 4; ++ni) {
        const int n = wave * 4 + ni;
        const int lcell = level_off(n) + pos;
        const int rcell = level_off(15 - n) + pos + n + 1;

        const f16x8 lv0 = *(const f16x8*)(CH16 + ((size_t)(0 * B_DIM + b) * NCELLS + lcell) * SZ + lane * 8);
        const f16x8 lv1 = *(const f16x8*)(CH16 + ((size_t)(1 * B_DIM + b) * NCELLS + lcell) * SZ + lane * 8);
        const f16x8 t0 = *(const f16x8*)&Ts[(0 * 16 + n) * 512 + lane * 8];
        const f16x8 t1 = *(const f16x8*)&Ts[(1 * 16 + n) * 512 + lane * 8];

        float d00 = 0.f, d01 = 0.f, d10 = 0.f, d11 = 0.f;
#pragma unroll
        for (int j = 0; j < 8; ++j) {
            const float c0 = (float)t0[j], c1 = (float)t1[j];
            const float l0 = (float)lv0[j], l1 = (float)lv1[j];
            d00 += l0 * c0; d01 += l0 * c1;
            d10 += l1 * c0; d11 += l1 * c1;
        }
#pragma unroll
        for (int o = 32; o > 0; o >>= 1) {
            d00 += __shfl_down(d00, o);
            d01 += __shfl_down(d01, o);
            d10 += __shfl_down(d10, o);
            d11 += __shfl_down(d11, o);
        }
        if (lane == 0) {
            const float ls0 = chart_s[(size_t)(0 * B_DIM + b) * NCELLS + lcell];
            const float ls1 = chart_s[(size_t)(1 * B_DIM + b) * NCELLS + lcell];
            const float rs0 = chart_s[(size_t)(0 * B_DIM + b) * NCELLS + rcell];
            const float rs1 = chart_s[(size_t)(1 * B_DIM + b) * NCELLS + rcell];
            const float inv = 1.0f / 16384.0f;   // undo x1024 (T') and x16 (lh)
            s_sh[n * 4 + 0] = d00 * inv + ls0 + rs0;
            s_sh[n * 4 + 1] = d01 * inv + ls0 + rs1;
            s_sh[n * 4 + 2] = d10 * inv + ls1 + rs0;
            s_sh[n * 4 + 3] = d11 * inv + ls1 + rs1;
        }
    }
    __syncthreads();

    if (threadIdx.x < 64) {
        float v = s_sh[lane];
        if (lane == 2 || lane == 3) v = NEGF;        // penalty mask
        float v1 = v; int i1 = lane;
#pragma unroll
        for (int o = 32; o > 0; o >>= 1) {
            float ov = __shfl_down(v1, o);
            int   oi = __shfl_down(i1, o);
            if (ov > v1 || (ov == v1 && oi < i1)) { v1 = ov; i1 = oi; }
        }
        v1 = __shfl(v1, 0); i1 = __shfl(i1, 0);
        float v2 = (lane == i1) ? -3.4e38f : v; int i2 = lane;
#pragma unroll
        for (int o = 32; o > 0; o >>= 1) {
            float ov = __shfl_down(v2, o);
            int   oi = __shfl_down(i2, o);
            if (ov > v2 || (ov == v2 && oi < i2)) { v2 = ov; i2 = oi; }
        }
        v2 = __shfl(v2, 0); i2 = __shfl(i2, 0);
        float v3 = (lane == i1 || lane == i2) ? -3.4e38f : v;
#pragma unroll
        for (int o = 32; o > 0; o >>= 1) {
            const float ov = __shfl_down(v3, o);
            if (ov > v3) v3 = ov;
        }
        v3 = __shfl(v3, 0);

        const int f = (v1 - v2 < DELTA) || (v2 - v3 < DELTA);
        const bool cand = (v >= v2 - DELTA);
        const unsigned long long mask = __ballot(cand);
        const int nc_full = __popcll(mask);
        const int nc = nc_full < MAXC ? nc_full : MAXC;
        int base = 0;
        if (lane == 0) {
            flags[row] = f ? nc : 0;
            flag_sh = f;
            if (f) base = atomicAdd(counter, nc);
            rowbase[row] = base;
            top_z[0] = i1; top_z[1] = i2;
            if (!f) emit_outputs(row, i1, i2, v1, v2, out);
        }
        base = __shfl(base, 0);
        if (f && cand) {
            const int rank = __popcll(mask & ((1ull << lane) - 1ull));
            if (rank < MAXC) items[base + rank] = ((uint32_t)row << 6) | (uint32_t)lane;
        }
    }
    __syncthreads();

    if (!flag_sh)
        gather_x(row, pos, b, top_z, chart_h, X, threadIdx.x);
}

// ---------------------------------------------------------------------------
// K3a: exact f32 eval, block per ITEM PAIR (both items share the 1MB mat
// sweep). Waves split the e-range; lane owns rh[8*lane..+8) in regs.
// ---------------------------------------------------------------------------
__global__ __launch_bounds__(256)
void refine_eval(const float* __restrict__ chart_h,
                 const float* __restrict__ chart_s,
                 const float* __restrict__ mat,
                 const uint32_t* __restrict__ items,
                 const int* __restrict__ counter,
                 float* __restrict__ exval)
{
    const int total = *counter;
    const int t = threadIdx.x;
    const int wave = t >> 6, lane = t & 63;

    __shared__ float lh_sh[2][512];
    __shared__ float psum[2][4];

    for (int p = blockIdx.x; 2 * p < total; p += gridDim.x) {
        const int it0 = 2 * p;
        const int it1v = (2 * p + 1 < total);
        const uint32_t item0 = items[it0];
        const uint32_t item1 = it1v ? items[it0 + 1] : item0;

        int rowA = item0 >> 6, zA = item0 & 63;
        int bA = rowA / L_DIM, posA = rowA % L_DIM;
        int nA = zA >> 2, lkA = (zA >> 1) & 1, rkA = zA & 1;
        int lcA = level_off(nA) + posA, rcA = level_off(15 - nA) + posA + nA + 1;
        int rowB = item1 >> 6, zB = item1 & 63;
        int bB = rowB / L_DIM, posB = rowB % L_DIM;
        int nB = zB >> 2, lkB = (zB >> 1) & 1, rkB = zB & 1;
        int lcB = level_off(nB) + posB, rcB = level_off(15 - nB) + posB + nB + 1;

        const float* lhA = chart_h + ((size_t)(lkA * B_DIM + bA) * NCELLS + lcA) * SZ;
        const float* rhA = chart_h + ((size_t)(rkA * B_DIM + bA) * NCELLS + rcA) * SZ;
        const float* lhB = chart_h + ((size_t)(lkB * B_DIM + bB) * NCELLS + lcB) * SZ;
        const float* rhB = chart_h + ((size_t)(rkB * B_DIM + bB) * NCELLS + rcB) * SZ;

        __syncthreads();
        lh_sh[0][t] = lhA[t]; lh_sh[0][t + 256] = lhA[t + 256];
        lh_sh[1][t] = lhB[t]; lh_sh[1][t + 256] = lhB[t + 256];
        const float4 rA0 = *(const float4*)(rhA + lane * 8);
        const float4 rA1 = *(const float4*)(rhA + lane * 8 + 4);
        const float4 rB0 = *(const float4*)(rhB + lane * 8);
        const float4 rB1 = *(const float4*)(rhB + lane * 8 + 4);
        __syncthreads();

        const float* mb = mat + (size_t)(wave * 128) * 512 + lane * 8;
        float a00 = 0.f, a01 = 0.f, b00 = 0.f, b01 = 0.f;
        for (int e = 0; e < 128; e += 2) {
            const float4 m0 = *(const float4*)(mb + (size_t)(e + 0) * 512);
            const float4 m1 = *(const float4*)(mb + (size_t)(e + 0) * 512 + 4);
            const float4 m2 = *(const float4*)(mb + (size_t)(e + 1) * 512);
            const float4 m3 = *(const float4*)(mb + (size_t)(e + 1) * 512 + 4);
            const int eg = wave * 128 + e;
            const float lA0 = lh_sh[0][eg],     lB0 = lh_sh[1][eg];
            const float lA1 = lh_sh[0][eg + 1], lB1 = lh_sh[1][eg + 1];
            const float dA0 = m0.x*rA0.x + m0.y*rA0.y + m0.z*rA0.z + m0.w*rA0.w
                            + m1.x*rA1.x + m1.y*rA1.y + m1.z*rA1.z + m1.w*rA1.w;
            const float dB0 = m0.x*rB0.x + m0.y*rB0.y + m0.z*rB0.z + m0.w*rB0.w
                            + m1.x*rB1.x + m1.y*rB1.y + m1.z*rB1.z + m1.w*rB1.w;
            const float dA1 = m2.x*rA0.x + m2.y*rA0.y + m2.z*rA0.z + m2.w*rA0.w
                            + m3.x*rA1.x + m3.y*rA1.y + m3.z*rA1.z + m3.w*rA1.w;
            const float dB1 = m2.x*rB0.x + m2.y*rB0.y + m2.z*rB0.z + m2.w*rB0.w
                            + m3.x*rB1.x + m3.y*rB1.y + m3.z*rB1.z + m3.w*rB1.w;
            a00 += lA0 * dA0; a01 += lA1 * dA1;
            b00 += lB0 * dB0; b01 += lB1 * dB1;
        }
        float sA = a00 + a01, sB = b00 + b01;
#pragma unroll
        for (int o = 32; o > 0; o >>= 1) {
            sA += __shfl_down(sA, o);
            sB += __shfl_down(sB, o);
        }
        if (lane == 0) { psum[0][wave] = sA; psum[1][wave] = sB; }
        __syncthreads();
        if (t == 0) {
            const float lsA = chart_s[(size_t)(lkA * B_DIM + bA) * NCELLS + lcA];
            const float rsA = chart_s[(size_t)(rkA * B_DIM + bA) * NCELLS + rcA];
            exval[it0] = psum[0][0] + psum[0][1] + psum[0][2] + psum[0][3] + lsA + rsA;
            if (it1v) {
                const float lsB = chart_s[(size_t)(lkB * B_DIM + bB) * NCELLS + lcB];
                const float rsB = chart_s[(size_t)(rkB * B_DIM + bB) * NCELLS + rcB];
                exval[it0 + 1] = psum[1][0] + psum[1][1] + psum[1][2] + psum[1][3] + lsB + rsB;
            }
        }
    }
}

// ---------------------------------------------------------------------------
// K3b: per flagged row, pick exact top-2 (z-ascending list + strict '>'
// replicates jax lowest-index tie-break), emit outputs + gather X.
// ---------------------------------------------------------------------------
__global__ __launch_bounds__(256)
void refine_pick(const float* __restrict__ chart_h,
                 const uint32_t* __restrict__ items,
                 const int* __restrict__ rowbase,
                 const int* __restrict__ flags,
                 const float* __restrict__ exval,
                 uint16_t* __restrict__ X,
                 float* __restrict__ out)
{
    const int row = blockIdx.x;
    const int nc = flags[row];
    if (nc == 0) return;
    const int b = row / L_DIM, pos = row % L_DIM;
    const int t = threadIdx.x;

    __shared__ int top_z[2];

    if (t == 0) {
        const int base = rowbase[row];
        float v1 = -3.4e38f; int c1 = -1;
        for (int c = 0; c < nc; ++c) {
            const float v = exval[base + c];
            if (v > v1) { v1 = v; c1 = c; }
        }
        float v2 = -3.4e38f; int c2 = -1;
        for (int c = 0; c < nc; ++c) {
            if (c == c1) continue;
            const float v = exval[base + c];
            if (v > v2) { v2 = v; c2 = c; }
        }
        const int i1 = (int)(items[base + c1] & 63u);
        const int i2 = (int)(items[base + c2] & 63u);
        top_z[0] = i1; top_z[1] = i2;
        emit_outputs(row, i1, i2, v1, v2, out);
    }
    __syncthreads();
    gather_x(row, pos, b, top_z, chart_h, X, t);
}

// ---------------------------------------------------------------------------
// transpose_wc: WcT[o][i] = bf16(Wc[i][o])
// ---------------------------------------------------------------------------
__global__ __launch_bounds__(256)
void transpose_wc(const float* __restrict__ Wc, uint16_t* __restrict__ WcT)
{
    __shared__ float tbuf[64][65];
    const int i0 = blockIdx.x * 64;
    const int o0 = blockIdx.y * 64;
    const int c = threadIdx.x & 63, r4 = threadIdx.x >> 6;
    for (int rr = r4; rr < 64; rr += 4)
        tbuf[rr][c] = Wc[(size_t)(i0 + rr) * 512 + o0 + c];
    __syncthreads();
    for (int rr = r4; rr < 64; rr += 4)
        WcT[(size_t)(o0 + rr) * 1024 + i0 + c] = f2bf(tbuf[c][rr]);
}

// ---------------------------------------------------------------------------
// K4: H = tanh(X @ WcT^T + bc)  (bf16 in, f32 out)
// ---------------------------------------------------------------------------
typedef __bf16 bf16x8 __attribute__((ext_vector_type(8)));

__global__ __launch_bounds__(256, 2)
void gemm_compose(const uint16_t* __restrict__ A,
                  const uint16_t* __restrict__ Bm,
                  const float* __restrict__ bias,
                  float* __restrict__ C,
                  int M, int Nn, int Kk)
{
    __shared__ uint16_t As[128 * 64];
    __shared__ uint16_t Bs[128 * 64];

    const int tid  = threadIdx.x;
    const int wave = tid >> 6, lane = tid & 63;
    const int m0 = blockIdx.x * 128, n0 = blockIdx.y * 128;
    const int wm = (wave & 1) * 64, wn = (wave >> 1) * 64;
    const int col_l = lane & 15, quad = lane >> 4;
    const int lrow = lane >> 3;
    const int lcol = (lane & 7) * 8;

    f32x4 acc[4][4];
#pragma unroll
    for (int i = 0; i < 4; ++i)
#pragma unroll
        for (int j = 0; j < 4; ++j) acc[i][j] = (f32x4){0.f, 0.f, 0.f, 0.f};

    for (int k0 = 0; k0 < Kk; k0 += 64) {
        __syncthreads();
#pragma unroll
        for (int i = 0; i < 4; ++i) {
            const int q = wave * 4 + i;
            const int r = q * 8 + lrow;
            GLD16(A  + (size_t)(m0 + r) * Kk + k0 + lcol, (char*)As + q * 1024);
            GLD16(Bm + (size_t)(n0 + r) * Kk + k0 + lcol, (char*)Bs + q * 1024);
        }
        __syncthreads();
#pragma unroll
        for (int kk = 0; kk < 64; kk += 32) {
            bf16x8 af[4], bfr[4];
#pragma unroll
            for (int mi = 0; mi < 4; ++mi)
                af[mi] = *(const bf16x8*)&As[(wm + mi * 16 + col_l) * 64 + kk + quad * 8];
#pragma unroll
            for (int ni = 0; ni < 4; ++ni)
                bfr[ni] = *(const bf16x8*)&Bs[(wn + ni * 16 + col_l) * 64 + kk + quad * 8];
#pragma unroll
            for (int mi = 0; mi < 4; ++mi)
#pragma unroll
                for (int ni = 0; ni < 4; ++ni)
                    acc[mi][ni] = __builtin_amdgcn_mfma_f32_16x16x32_bf16(
                        af[mi], bfr[ni], acc[mi][ni], 0, 0, 0);
        }
    }

#pragma unroll
    for (int ni = 0; ni < 4; ++ni) {
        const int ncol = n0 + wn + ni * 16 + col_l;
        const float bv = bias[ncol];
#pragma unroll
        for (int mi = 0; mi < 4; ++mi) {
            const int mrow = m0 + wm + mi * 16 + quad * 4;
#pragma unroll
            for (int r = 0; r < 4; ++r)
                C[(size_t)(mrow + r) * Nn + ncol] = tanhf(acc[mi][ni][r] + bv);
        }
    }
}

// ---------------------------------------------------------------------------
// K5: unit-normalize H rows -> topk_h
// ---------------------------------------------------------------------------
__global__ __launch_bounds__(256)
void norm_rows(const float* __restrict__ H, float* __restrict__ out)
{
    const int row = blockIdx.x;
    const float* h = H + (size_t)row * SZ;
    const int t = threadIdx.x;
    const int wave = t >> 6, lane = t & 63;
    const float a = h[t], c = h[t + 256];
    float ss = a * a + c * c;
#pragma unroll
    for (int o = 32; o > 0; o >>= 1) ss += __shfl_down(ss, o);
    __shared__ float wsum[4];
    if (lane == 0) wsum[wave] = ss;
    __syncthreads();
    const float inv = rsqrtf(wsum[0] + wsum[1] + wsum[2] + wsum[3]);
    out[(size_t)row * SZ + t]       = a * inv;
    out[(size_t)row * SZ + t + 256] = c * inv;
}

// ---------------------------------------------------------------------------
extern "C" void kernel_launch(void* const* d_in, const int* in_sizes, int n_in,
                              void* d_out, int out_size, void* d_ws, size_t ws_size,
                              hipStream_t stream)
{
    const float* chart_h = (const float*)d_in[0];
    const float* chart_s = (const float*)d_in[1];
    const float* mat = (const float*)d_in[4];
    const float* Wc  = (const float*)d_in[5];
    const float* bc  = (const float*)d_in[6];
    float* out = (float*)d_out;

    // workspace (peak ~66.5 MB; T16 deleted):
    //   MAT16 f16 packed       @ 0            (   524,288)  alive -> K2'
    //   ITEMS u32[49152]       @ 524,288      (   196,608)
    //   EXVAL f32[49152]       @ 720,896      (   196,608)
    //   RBASE i32[1536]        @ 917,504      (     6,144)
    //   CNT   i32              @ 923,648      (       256)
    //   FLAGS i32[1536]        @ 923,904      (     6,144)
    //   X     bf16[3072][1024] @ 930,048      ( 6,291,456)
    //   CH16  f16 [57856][512] @ 7,221,504    (59,244,544)  alive P1->K2'
    //   WcT   bf16[512][1024]  @ 7,221,504    (overlays CH16 after K2')
    //   H     f32 [3072][512]  @ 8,270,080    (overlays CH16 after K2')
    char* ws = (char*)d_ws;
    _Float16* MAT16 = (_Float16*)ws;
    uint32_t* ITEMS = (uint32_t*)(ws + 524288);
    float*    EXVAL = (float*)(ws + 720896);
    int*      RBASE = (int*)(ws + 917504);
    int*      CNT   = (int*)(ws + 923648);
    int*      FLAGS = (int*)(ws + 923904);
    uint16_t* X     = (uint16_t*)(ws + 930048);
    _Float16* CH16  = (_Float16*)(ws + 7221504);
    uint16_t* WcT   = (uint16_t*)(ws + 7221504);
    float*    H     = (float*)(ws + 8270080);

    hipMemsetAsync(CNT, 0, 4, stream);
    // P0: packed mat16 (fragment-chunk order, f16(64*mat))
    prep_mat<<<dim3(128), 256, 0, stream>>>(mat, MAT16);
    // P1: CH16 = f16(16*chart_h), pure streaming convert (64B/thread)
    conv_h<<<dim3(7232), 256, 0, stream>>>(chart_h, CH16);
    // K2': fused T-slice MFMA + cheap scores + top3 + candidate queue
    score_fused<<<dim3(B_DIM * L_DIM), 256, 0, stream>>>(chart_h, CH16, MAT16,
                                                         chart_s, ITEMS, RBASE,
                                                         CNT, FLAGS, X, out);
    // (MAT16/CH16 dead from here; WcT/H overlay CH16 region)
    transpose_wc<<<dim3(16, 8), 256, 0, stream>>>(Wc, WcT);
    // K3a: exact eval, block per item pair (mat shared within pair)
    refine_eval<<<dim3(1024), 256, 0, stream>>>(chart_h, chart_s, mat, ITEMS, CNT, EXVAL);
    // K3b: per-row exact top-2 + outputs + X
    refine_pick<<<dim3(B_DIM * L_DIM), 256, 0, stream>>>(chart_h, ITEMS, RBASE, FLAGS,
                                                         EXVAL, X, out);
    // K4: H = tanh(X @ WcT^T + bc)
    gemm_compose<<<dim3(24, 4), 256, 0, stream>>>(X, WcT, bc, H, 3072, 512, 1024);
    // K5: topk_h = H / ||H||
    norm_rows<<<dim3(3072), 256, 0, stream>>>(H, out);
}

// Round 12
// 323.084 us; speedup vs baseline: 1.0719x; 1.0719x over previous
//
#include <hip/hip_runtime.h>
#include <cstdint>
#include <cstddef>

// ---------------------------------------------------------------------------
// Problem constants (LEVEL=16, LENGTH=64, TOPK=2, SIZE=512, BATCH=32)
// Cheap path: f16 MFMA scores; rows with cheap top-2/3 gaps < DELTA=0.25 get
// exact f32 refinement over candidates {z: cheap[z] >= cheap_top2 - DELTA}.
//
// Ledger: total = poison 72 + conv + fused(K1+K2) + rest 136.
//   r13: split K1=91, K2=16, conv=0            -> 315 (prev session best)
//   r16: split K1=73 (all-DMA+L2-B), conv=44   -> 342
//   r18: FUSED score_fused=94, conv=44         -> 346. Fusion works (FETCH
//        59MB, T16 round-trip gone) but 2 blocks/CU (LDS 66KB) -> 3 serial
//        generations, occupancy 21%, all pipes ~10%: same latency disease.
// r19: (a) overlay Ts onto Arh (never live together; barrier between
//      Phase B last-read and Phase C write): LDS 66->34KB -> 4 blocks/CU,
//      generations 3->1.5, L2 B-load chains finally have co-resident
//      partners to hide under (r12's occupancy lever, now without the
//      barrier rhythm that nulled it). __launch_bounds__(256,4).
//      (b) conv_h grid-stride 2048 blocks (G11 memory-bound recipe).
// ---------------------------------------------------------------------------
#define B_DIM   32
#define L_DIM   48
#define NCELLS  904
#define SZ      512
#define NEGF    (-1e8f)
#define DELTA   0.25f
#define MAXC    32          // max candidates per row kept (z-ascending)

// d_out layout (f32), outputs concatenated flat in return order
#define OFF_S   1572864
#define OFF_N   1575936
#define OFF_L   1579008
#define OFF_R   1582080

typedef _Float16  f16x8 __attribute__((ext_vector_type(8)));
typedef float     f32x4 __attribute__((ext_vector_type(4)));

static __device__ __forceinline__ uint16_t f2bf(float f) {
    uint32_t u = __builtin_bit_cast(uint32_t, f);
    u += 0x7fffu + ((u >> 16) & 1u);
    return (uint16_t)(u >> 16);
}

#define GLD16(gp, lp) __builtin_amdgcn_global_load_lds(                        \
        (__attribute__((address_space(1))) void*)(gp),                         \
        (__attribute__((address_space(3))) void*)(lp), 16, 0, 0)

static __device__ __forceinline__ int level_off(int n) {
    return n * 64 - (n * (n - 1)) / 2;
}

// ---------------------------------------------------------------------------
// P0: pack mat into fragment-chunk order, f16(64*mat).
// Chunk c = ksub*32 + q (ksub=k/32 in 0..15, q=n/16 in 0..31), 1KB each:
//   P[c*512 + lane*8 + j] = f16(64 * mat[16q + (lane&15)][32*ksub + (lane>>4)*8 + j])
// A wave reading P + c*512 + lane*8 gets fragment (q, ksub) lane-linear as
// one contiguous, fully-coalesced 1KB transaction.
// ---------------------------------------------------------------------------
__global__ __launch_bounds__(256)
void prep_mat(const float* __restrict__ mat, _Float16* __restrict__ P)
{
    const int tg   = blockIdx.x * 256 + threadIdx.x;   // 0..32767
    const int c    = tg >> 6, lane = tg & 63;
    const int srow = 16 * (c & 31) + (lane & 15);
    const int scol = 32 * (c >> 5) + (lane >> 4) * 8;
    const float4 a = *(const float4*)(mat + (size_t)srow * 512 + scol);
    const float4 b = *(const float4*)(mat + (size_t)srow * 512 + scol + 4);
    f16x8 w;
    w[0]=(_Float16)(a.x*64.f); w[1]=(_Float16)(a.y*64.f);
    w[2]=(_Float16)(a.z*64.f); w[3]=(_Float16)(a.w*64.f);
    w[4]=(_Float16)(b.x*64.f); w[5]=(_Float16)(b.y*64.f);
    w[6]=(_Float16)(b.z*64.f); w[7]=(_Float16)(b.w*64.f);
    *(f16x8*)(P + (size_t)tg * 8) = w;
}

// ---------------------------------------------------------------------------
// P1: CH16 = f16(16*chart_h), row-major [57856][512]. Grid-stride streaming
// pass (2048 blocks), 32B out per thread-iter, perfectly coalesced.
// ---------------------------------------------------------------------------
__global__ __launch_bounds__(256)
void conv_h(const float* __restrict__ x, _Float16* __restrict__ y)
{
    const size_t stride = (size_t)gridDim.x * 256;
    const size_t nvec = (size_t)57856 * 512 / 8;     // 3,702,784 f16x8 units
    for (size_t v = (size_t)blockIdx.x * 256 + threadIdx.x; v < nvec; v += stride) {
        const size_t i = v * 8;
        const float4 a = *(const float4*)(x + i);
        const float4 b = *(const float4*)(x + i + 4);
        f16x8 w;
        w[0]=(_Float16)(a.x*16.f); w[1]=(_Float16)(a.y*16.f);
        w[2]=(_Float16)(a.z*16.f); w[3]=(_Float16)(a.w*16.f);
        w[4]=(_Float16)(b.x*16.f); w[5]=(_Float16)(b.y*16.f);
        w[6]=(_Float16)(b.z*16.f); w[7]=(_Float16)(b.w*16.f);
        *(f16x8*)(y + i) = w;
    }
}

// ---------------------------------------------------------------------------
// shared epilogue helpers
// ---------------------------------------------------------------------------
static __device__ __forceinline__ void emit_outputs(
    int row, int i1, int i2, float v1, float v2, float* out)
{
    out[OFF_S + row * 2 + 0] = v1;
    out[OFF_S + row * 2 + 1] = v2;
    out[OFF_N + row * 2 + 0] = (float)(i1 >> 2);
    out[OFF_N + row * 2 + 1] = (float)(i2 >> 2);
    out[OFF_L + row * 2 + 0] = (float)((i1 >> 1) & 1);
    out[OFF_L + row * 2 + 1] = (float)((i2 >> 1) & 1);
    out[OFF_R + row * 2 + 0] = (float)(i1 & 1);
    out[OFF_R + row * 2 + 1] = (float)(i2 & 1);
}

static __device__ __forceinline__ void gather_x(
    int row, int pos, int b, const int* top_z,
    const float* __restrict__ chart_h, uint16_t* __restrict__ X, int tid)
{
#pragma unroll
    for (int kq = 0; kq < 2; ++kq) {
        const int z = top_z[kq];
        const int n = z >> 2, lk = (z >> 1) & 1, rk = z & 1;
        const int lcell = level_off(n) + pos;
        const int rcell = level_off(15 - n) + pos + n + 1;
        const float* srcl = chart_h + ((size_t)(lk * B_DIM + b) * NCELLS + lcell) * SZ;
        const float* srcr = chart_h + ((size_t)(rk * B_DIM + b) * NCELLS + rcell) * SZ;
        uint16_t* dst = X + ((size_t)row * 2 + kq) * 1024;
        const int e = tid * 2;
        const float2 a = *(const float2*)(srcl + e);
        const float2 c = *(const float2*)(srcr + e);
        *(uint32_t*)(dst + e)       = (uint32_t)f2bf(a.x) | ((uint32_t)f2bf(a.y) << 16);
        *(uint32_t*)(dst + 512 + e) = (uint32_t)f2bf(c.x) | ((uint32_t)f2bf(c.y) << 16);
    }
}

// ---------------------------------------------------------------------------
// K2': FUSED per-(b,pos) kernel. Grid 1536, 4 waves, 4 blocks/CU.
// Phase A (stage): 32 rh rows (r = k*16+n -> rcell) via contiguous-1KB
//   GLD16 from CH16, XOR-unit source swizzle, into buf (as Arh, 32KB).
// Phase B (MFMA): T-slice[32][512] = Arh @ P^T. Wave w owns cols 128w..+128:
//   acc[2][8]; per w16: 2 swizzled af LDS reads + 8 bf 1KB loads direct
//   from packed P (L2) + 16 MFMA. Barrier-free (r16-verified schedule).
// [barrier]  (all waves done reading Arh)
// Phase C: buf (as Ts[32][512]) = f16(acc)  -- overlays dead Arh.
// [barrier]
// Phase D (dot/topk): K2 code verbatim, t0/t1 from Ts LDS, lh from CH16.
// ---------------------------------------------------------------------------
__global__ __launch_bounds__(256, 4)
void score_fused(const float* __restrict__ chart_h,   // f32 (gather_x only)
                 const _Float16* __restrict__ CH16,   // f16(16*chart_h)
                 const _Float16* __restrict__ P,      // packed mat16
                 const float* __restrict__ chart_s,
                 uint32_t* __restrict__ items,
                 int* __restrict__ rowbase,
                 int* __restrict__ counter,
                 int* __restrict__ flags,
                 uint16_t* __restrict__ X,
                 float* __restrict__ out)
{
    __shared__ _Float16 buf[32 * 512];   // 32 KB: Arh (A..B), then Ts (C..D)
    __shared__ float s_sh[64];
    __shared__ int top_z[2];
    __shared__ int flag_sh;

    const int row = blockIdx.x;
    const int b   = row / L_DIM;
    const int pos = row % L_DIM;
    const int t = threadIdx.x;
    const int wave = t >> 6, lane = t & 63;
    const int col_l = lane & 15, quad = lane >> 4;

    // ---- Phase A: stage 32 rh rows (row r = k*16+n) into buf (Arh) ----
#pragma unroll
    for (int i = 0; i < 8; ++i) {
        const int r = wave * 8 + i;
        const int k = r >> 4, n = r & 15;
        const int rcell = level_off(15 - n) + pos + n + 1;
        const size_t grow = (size_t)(k * B_DIM + b) * NCELLS + rcell;
        GLD16(CH16 + grow * 512 + ((lane ^ (r & 7)) * 8),
              (char*)buf + r * 1024);
    }
    __syncthreads();                     // drain DMA

    // ---- Phase B: MFMA (wave owns cols wave*128..+128), barrier-free ----
    f32x4 acc[2][8];
#pragma unroll
    for (int i = 0; i < 2; ++i)
#pragma unroll
        for (int j = 0; j < 8; ++j) acc[i][j] = (f32x4){0.f, 0.f, 0.f, 0.f};

#pragma unroll 4
    for (int w16 = 0; w16 < 16; ++w16) {
        f16x8 af[2];
#pragma unroll
        for (int mi = 0; mi < 2; ++mi) {
            const int r = mi * 16 + col_l;
            const int u = w16 * 4 + quad;
            af[mi] = *(const f16x8*)&buf[r * 512 + (u ^ (r & 7)) * 8];
        }
#pragma unroll
        for (int ni = 0; ni < 8; ++ni) {
            const int c = w16 * 32 + wave * 8 + ni;
            const f16x8 bf = *(const f16x8*)(P + (size_t)c * 512 + lane * 8);
#pragma unroll
            for (int mi = 0; mi < 2; ++mi)
                acc[mi][ni] = __builtin_amdgcn_mfma_f32_16x16x32_f16(
                    af[mi], bf, acc[mi][ni], 0, 0, 0);
        }
    }
    __syncthreads();                     // Arh reads complete everywhere

    // ---- Phase C: buf becomes Ts = f16(acc); col=lane&15, row=quad*4+reg --
#pragma unroll
    for (int mi = 0; mi < 2; ++mi)
#pragma unroll
        for (int ni = 0; ni < 8; ++ni)
#pragma unroll
            for (int rr = 0; rr < 4; ++rr)
                buf[(mi * 16 + quad * 4 + rr) * 512 + wave * 128 + ni * 16 + col_l]
                    = (_Float16)acc[mi][ni][rr];
    __syncthreads();                     // Ts visible to all waves

    // ---- Phase D: dot + topk (T from Ts LDS) ----
#pragma unroll
    for (int ni = 0; ni < 4; ++ni) {
        const int n = wave * 4 + ni;
        const int lcell = level_off(n) + pos;
        const int rcell = level_off(15 - n) + pos + n + 1;

        const f16x8 lv0 = *(const f16x8*)(CH16 + ((size_t)(0 * B_DIM + b) * NCELLS + lcell) * SZ + lane * 8);
        const f16x8 lv1 = *(const f16x8*)(CH16 + ((size_t)(1 * B_DIM + b) * NCELLS + lcell) * SZ + lane * 8);
        const f16x8 t0 = *(const f16x8*)&buf[(0 * 16 + n) * 512 + lane * 8];
        const f16x8 t1 = *(const f16x8*)&buf[(1 * 16 + n) * 512 + lane * 8];

        float d00 = 0.f, d01 = 0.f, d10 = 0.f, d11 = 0.f;
#pragma unroll
        for (int j = 0; j < 8; ++j) {
            const float c0 = (float)t0[j], c1 = (float)t1[j];
            const float l0 = (float)lv0[j], l1 = (float)lv1[j];
            d00 += l0 * c0; d01 += l0 * c1;
            d10 += l1 * c0; d11 += l1 * c1;
        }
#pragma unroll
        for (int o = 32; o > 0; o >>= 1) {
            d00 += __shfl_down(d00, o);
            d01 += __shfl_down(d01, o);
            d10 += __shfl_down(d10, o);
            d11 += __shfl_down(d11, o);
        }
        if (lane == 0) {
            const float ls0 = chart_s[(size_t)(0 * B_DIM + b) * NCELLS + lcell];
            const float ls1 = chart_s[(size_t)(1 * B_DIM + b) * NCELLS + lcell];
            const float rs0 = chart_s[(size_t)(0 * B_DIM + b) * NCELLS + rcell];
            const float rs1 = chart_s[(size_t)(1 * B_DIM + b) * NCELLS + rcell];
            const float inv = 1.0f / 16384.0f;   // undo x1024 (T') and x16 (lh)
            s_sh[n * 4 + 0] = d00 * inv + ls0 + rs0;
            s_sh[n * 4 + 1] = d01 * inv + ls0 + rs1;
            s_sh[n * 4 + 2] = d10 * inv + ls1 + rs0;
            s_sh[n * 4 + 3] = d11 * inv + ls1 + rs1;
        }
    }
    __syncthreads();

    if (threadIdx.x < 64) {
        float v = s_sh[lane];
        if (lane == 2 || lane == 3) v = NEGF;        // penalty mask
        float v1 = v; int i1 = lane;
#pragma unroll
        for (int o = 32; o > 0; o >>= 1) {
            float ov = __shfl_down(v1, o);
            int   oi = __shfl_down(i1, o);
            if (ov > v1 || (ov == v1 && oi < i1)) { v1 = ov; i1 = oi; }
        }
        v1 = __shfl(v1, 0); i1 = __shfl(i1, 0);
        float v2 = (lane == i1) ? -3.4e38f : v; int i2 = lane;
#pragma unroll
        for (int o = 32; o > 0; o >>= 1) {
            float ov = __shfl_down(v2, o);
            int   oi = __shfl_down(i2, o);
            if (ov > v2 || (ov == v2 && oi < i2)) { v2 = ov; i2 = oi; }
        }
        v2 = __shfl(v2, 0); i2 = __shfl(i2, 0);
        float v3 = (lane == i1 || lane == i2) ? -3.4e38f : v;
#pragma unroll
        for (int o = 32; o > 0; o >>= 1) {
            const float ov = __shfl_down(v3, o);
            if (ov > v3) v3 = ov;
        }
        v3 = __shfl(v3, 0);

        const int f = (v1 - v2 < DELTA) || (v2 - v3 < DELTA);
        const bool cand = (v >= v2 - DELTA);
        const unsigned long long mask = __ballot(cand);
        const int nc_full = __popcll(mask);
        const int nc = nc_full < MAXC ? nc_full : MAXC;
        int base = 0;
        if (lane == 0) {
            flags[row] = f ? nc : 0;
            flag_sh = f;
            if (f) base = atomicAdd(counter, nc);
            rowbase[row] = base;
            top_z[0] = i1; top_z[1] = i2;
            if (!f) emit_outputs(row, i1, i2, v1, v2, out);
        }
        base = __shfl(base, 0);
        if (f && cand) {
            const int rank = __popcll(mask & ((1ull << lane) - 1ull));
            if (rank < MAXC) items[base + rank] = ((uint32_t)row << 6) | (uint32_t)lane;
        }
    }
    __syncthreads();

    if (!flag_sh)
        gather_x(row, pos, b, top_z, chart_h, X, threadIdx.x);
}

// ---------------------------------------------------------------------------
// K3a: exact f32 eval, block per ITEM PAIR (both items share the 1MB mat
// sweep). Waves split the e-range; lane owns rh[8*lane..+8) in regs.
// ---------------------------------------------------------------------------
__global__ __launch_bounds__(256)
void refine_eval(const float* __restrict__ chart_h,
                 const float* __restrict__ chart_s,
                 const float* __restrict__ mat,
                 const uint32_t* __restrict__ items,
                 const int* __restrict__ counter,
                 float* __restrict__ exval)
{
    const int total = *counter;
    const int t = threadIdx.x;
    const int wave = t >> 6, lane = t & 63;

    __shared__ float lh_sh[2][512];
    __shared__ float psum[2][4];

    for (int p = blockIdx.x; 2 * p < total; p += gridDim.x) {
        const int it0 = 2 * p;
        const int it1v = (2 * p + 1 < total);
        const uint32_t item0 = items[it0];
        const uint32_t item1 = it1v ? items[it0 + 1] : item0;

        int rowA = item0 >> 6, zA = item0 & 63;
        int bA = rowA / L_DIM, posA = rowA % L_DIM;
        int nA = zA >> 2, lkA = (zA >> 1) & 1, rkA = zA & 1;
        int lcA = level_off(nA) + posA, rcA = level_off(15 - nA) + posA + nA + 1;
        int rowB = item1 >> 6, zB = item1 & 63;
        int bB = rowB / L_DIM, posB = rowB % L_DIM;
        int nB = zB >> 2, lkB = (zB >> 1) & 1, rkB = zB & 1;
        int lcB = level_off(nB) + posB, rcB = level_off(15 - nB) + posB + nB + 1;

        const float* lhA = chart_h + ((size_t)(lkA * B_DIM + bA) * NCELLS + lcA) * SZ;
        const float* rhA = chart_h + ((size_t)(rkA * B_DIM + bA) * NCELLS + rcA) * SZ;
        const float* lhB = chart_h + ((size_t)(lkB * B_DIM + bB) * NCELLS + lcB) * SZ;
        const float* rhB = chart_h + ((size_t)(rkB * B_DIM + bB) * NCELLS + rcB) * SZ;

        __syncthreads();
        lh_sh[0][t] = lhA[t]; lh_sh[0][t + 256] = lhA[t + 256];
        lh_sh[1][t] = lhB[t]; lh_sh[1][t + 256] = lhB[t + 256];
        const float4 rA0 = *(const float4*)(rhA + lane * 8);
        const float4 rA1 = *(const float4*)(rhA + lane * 8 + 4);
        const float4 rB0 = *(const float4*)(rhB + lane * 8);
        const float4 rB1 = *(const float4*)(rhB + lane * 8 + 4);
        __syncthreads();

        const float* mb = mat + (size_t)(wave * 128) * 512 + lane * 8;
        float a00 = 0.f, a01 = 0.f, b00 = 0.f, b01 = 0.f;
        for (int e = 0; e < 128; e += 2) {
            const float4 m0 = *(const float4*)(mb + (size_t)(e + 0) * 512);
            const float4 m1 = *(const float4*)(mb + (size_t)(e + 0) * 512 + 4);
            const float4 m2 = *(const float4*)(mb + (size_t)(e + 1) * 512);
            const float4 m3 = *(const float4*)(mb + (size_t)(e + 1) * 512 + 4);
            const int eg = wave * 128 + e;
            const float lA0 = lh_sh[0][eg],     lB0 = lh_sh[1][eg];
            const float lA1 = lh_sh[0][eg + 1], lB1 = lh_sh[1][eg + 1];
            const float dA0 = m0.x*rA0.x + m0.y*rA0.y + m0.z*rA0.z + m0.w*rA0.w
                            + m1.x*rA1.x + m1.y*rA1.y + m1.z*rA1.z + m1.w*rA1.w;
            const float dB0 = m0.x*rB0.x + m0.y*rB0.y + m0.z*rB0.z + m0.w*rB0.w
                            + m1.x*rB1.x + m1.y*rB1.y + m1.z*rB1.z + m1.w*rB1.w;
            const float dA1 = m2.x*rA0.x + m2.y*rA0.y + m2.z*rA0.z + m2.w*rA0.w
                            + m3.x*rA1.x + m3.y*rA1.y + m3.z*rA1.z + m3.w*rA1.w;
            const float dB1 = m2.x*rB0.x + m2.y*rB0.y + m2.z*rB0.z + m2.w*rB0.w
                            + m3.x*rB1.x + m3.y*rB1.y + m3.z*rB1.z + m3.w*rB1.w;
            a00 += lA0 * dA0; a01 += lA1 * dA1;
            b00 += lB0 * dB0; b01 += lB1 * dB1;
        }
        float sA = a00 + a01, sB = b00 + b01;
#pragma unroll
        for (int o = 32; o > 0; o >>= 1) {
            sA += __shfl_down(sA, o);
            sB += __shfl_down(sB, o);
        }
        if (lane == 0) { psum[0][wave] = sA; psum[1][wave] = sB; }
        __syncthreads();
        if (t == 0) {
            const float lsA = chart_s[(size_t)(lkA * B_DIM + bA) * NCELLS + lcA];
            const float rsA = chart_s[(size_t)(rkA * B_DIM + bA) * NCELLS + rcA];
            exval[it0] = psum[0][0] + psum[0][1] + psum[0][2] + psum[0][3] + lsA + rsA;
            if (it1v) {
                const float lsB = chart_s[(size_t)(lkB * B_DIM + bB) * NCELLS + lcB];
                const float rsB = chart_s[(size_t)(rkB * B_DIM + bB) * NCELLS + rcB];
                exval[it0 + 1] = psum[1][0] + psum[1][1] + psum[1][2] + psum[1][3] + lsB + rsB;
            }
        }
    }
}

// ---------------------------------------------------------------------------
// K3b: per flagged row, pick exact top-2 (z-ascending list + strict '>'
// replicates jax lowest-index tie-break), emit outputs + gather X.
// ---------------------------------------------------------------------------
__global__ __launch_bounds__(256)
void refine_pick(const float* __restrict__ chart_h,
                 const uint32_t* __restrict__ items,
                 const int* __restrict__ rowbase,
                 const int* __restrict__ flags,
                 const float* __restrict__ exval,
                 uint16_t* __restrict__ X,
                 float* __restrict__ out)
{
    const int row = blockIdx.x;
    const int nc = flags[row];
    if (nc == 0) return;
    const int b = row / L_DIM, pos = row % L_DIM;
    const int t = threadIdx.x;

    __shared__ int top_z[2];

    if (t == 0) {
        const int base = rowbase[row];
        float v1 = -3.4e38f; int c1 = -1;
        for (int c = 0; c < nc; ++c) {
            const float v = exval[base + c];
            if (v > v1) { v1 = v; c1 = c; }
        }
        float v2 = -3.4e38f; int c2 = -1;
        for (int c = 0; c < nc; ++c) {
            if (c == c1) continue;
            const float v = exval[base + c];
            if (v > v2) { v2 = v; c2 = c; }
        }
        const int i1 = (int)(items[base + c1] & 63u);
        const int i2 = (int)(items[base + c2] & 63u);
        top_z[0] = i1; top_z[1] = i2;
        emit_outputs(row, i1, i2, v1, v2, out);
    }
    __syncthreads();
    gather_x(row, pos, b, top_z, chart_h, X, t);
}

// ---------------------------------------------------------------------------
// transpose_wc: WcT[o][i] = bf16(Wc[i][o])
// ---------------------------------------------------------------------------
__global__ __launch_bounds__(256)
void transpose_wc(const float* __restrict__ Wc, uint16_t* __restrict__ WcT)
{
    __shared__ float tbuf[64][65];
    const int i0 = blockIdx.x * 64;
    const int o0 = blockIdx.y * 64;
    const int c = threadIdx.x & 63, r4 = threadIdx.x >> 6;
    for (int rr = r4; rr < 64; rr += 4)
        tbuf[rr][c] = Wc[(size_t)(i0 + rr) * 512 + o0 + c];
    __syncthreads();
    for (int rr = r4; rr < 64; rr += 4)
        WcT[(size_t)(o0 + rr) * 1024 + i0 + c] = f2bf(tbuf[c][rr]);
}

// ---------------------------------------------------------------------------
// K4: H = tanh(X @ WcT^T + bc)  (bf16 in, f32 out)
// ---------------------------------------------------------------------------
typedef __bf16 bf16x8 __attribute__((ext_vector_type(8)));

__global__ __launch_bounds__(256, 2)
void gemm_compose(const uint16_t* __restrict__ A,
                  const uint16_t* __restrict__ Bm,
                  const float* __restrict__ bias,
                  float* __restrict__ C,
                  int M, int Nn, int Kk)
{
    __shared__ uint16_t As[128 * 64];
    __shared__ uint16_t Bs[128 * 64];

    const int tid  = threadIdx.x;
    const int wave = tid >> 6, lane = tid & 63;
    const int m0 = blockIdx.x * 128, n0 = blockIdx.y * 128;
    const int wm = (wave & 1) * 64, wn = (wave >> 1) * 64;
    const int col_l = lane & 15, quad = lane >> 4;
    const int lrow = lane >> 3;
    const int lcol = (lane & 7) * 8;

    f32x4 acc[4][4];
#pragma unroll
    for (int i = 0; i < 4; ++i)
#pragma unroll
        for (int j = 0; j < 4; ++j) acc[i][j] = (f32x4){0.f, 0.f, 0.f, 0.f};

    for (int k0 = 0; k0 < Kk; k0 += 64) {
        __syncthreads();
#pragma unroll
        for (int i = 0; i < 4; ++i) {
            const int q = wave * 4 + i;
            const int r = q * 8 + lrow;
            GLD16(A  + (size_t)(m0 + r) * Kk + k0 + lcol, (char*)As + q * 1024);
            GLD16(Bm + (size_t)(n0 + r) * Kk + k0 + lcol, (char*)Bs + q * 1024);
        }
        __syncthreads();
#pragma unroll
        for (int kk = 0; kk < 64; kk += 32) {
            bf16x8 af[4], bfr[4];
#pragma unroll
            for (int mi = 0; mi < 4; ++mi)
                af[mi] = *(const bf16x8*)&As[(wm + mi * 16 + col_l) * 64 + kk + quad * 8];
#pragma unroll
            for (int ni = 0; ni < 4; ++ni)
                bfr[ni] = *(const bf16x8*)&Bs[(wn + ni * 16 + col_l) * 64 + kk + quad * 8];
#pragma unroll
            for (int mi = 0; mi < 4; ++mi)
#pragma unroll
                for (int ni = 0; ni < 4; ++ni)
                    acc[mi][ni] = __builtin_amdgcn_mfma_f32_16x16x32_bf16(
                        af[mi], bfr[ni], acc[mi][ni], 0, 0, 0);
        }
    }

#pragma unroll
    for (int ni = 0; ni < 4; ++ni) {
        const int ncol = n0 + wn + ni * 16 + col_l;
        const float bv = bias[ncol];
#pragma unroll
        for (int mi = 0; mi < 4; ++mi) {
            const int mrow = m0 + wm + mi * 16 + quad * 4;
#pragma unroll
            for (int r = 0; r < 4; ++r)
                C[(size_t)(mrow + r) * Nn + ncol] = tanhf(acc[mi][ni][r] + bv);
        }
    }
}

// ---------------------------------------------------------------------------
// K5: unit-normalize H rows -> topk_h
// ---------------------------------------------------------------------------
__global__ __launch_bounds__(256)
void norm_rows(const float* __restrict__ H, float* __restrict__ out)
{
    const int row = blockIdx.x;
    const float* h = H + (size_t)row * SZ;
    const int t = threadIdx.x;
    const int wave = t >> 6, lane = t & 63;
    const float a = h[t], c = h[t + 256];
    float ss = a * a + c * c;
#pragma unroll
    for (int o = 32; o > 0; o >>= 1) ss += __shfl_down(ss, o);
    __shared__ float wsum[4];
    if (lane == 0) wsum[wave] = ss;
    __syncthreads();
    const float inv = rsqrtf(wsum[0] + wsum[1] + wsum[2] + wsum[3]);
    out[(size_t)row * SZ + t]       = a * inv;
    out[(size_t)row * SZ + t + 256] = c * inv;
}

// ---------------------------------------------------------------------------
extern "C" void kernel_launch(void* const* d_in, const int* in_sizes, int n_in,
                              void* d_out, int out_size, void* d_ws, size_t ws_size,
                              hipStream_t stream)
{
    const float* chart_h = (const float*)d_in[0];
    const float* chart_s = (const float*)d_in[1];
    const float* mat = (const float*)d_in[4];
    const float* Wc  = (const float*)d_in[5];
    const float* bc  = (const float*)d_in[6];
    float* out = (float*)d_out;

    // workspace (peak ~66.5 MB):
    //   MAT16 f16 packed       @ 0            (   524,288)  alive -> K2'
    //   ITEMS u32[49152]       @ 524,288      (   196,608)
    //   EXVAL f32[49152]       @ 720,896      (   196,608)
    //   RBASE i32[1536]        @ 917,504      (     6,144)
    //   CNT   i32              @ 923,648      (       256)
    //   FLAGS i32[1536]        @ 923,904      (     6,144)
    //   X     bf16[3072][1024] @ 930,048      ( 6,291,456)
    //   CH16  f16 [57856][512] @ 7,221,504    (59,244,544)  alive P1->K2'
    //   WcT   bf16[512][1024]  @ 7,221,504    (overlays CH16 after K2')
    //   H     f32 [3072][512]  @ 8,270,080    (overlays CH16 after K2')
    char* ws = (char*)d_ws;
    _Float16* MAT16 = (_Float16*)ws;
    uint32_t* ITEMS = (uint32_t*)(ws + 524288);
    float*    EXVAL = (float*)(ws + 720896);
    int*      RBASE = (int*)(ws + 917504);
    int*      CNT   = (int*)(ws + 923648);
    int*      FLAGS = (int*)(ws + 923904);
    uint16_t* X     = (uint16_t*)(ws + 930048);
    _Float16* CH16  = (_Float16*)(ws + 7221504);
    uint16_t* WcT   = (uint16_t*)(ws + 7221504);
    float*    H     = (float*)(ws + 8270080);

    hipMemsetAsync(CNT, 0, 4, stream);
    // P0: packed mat16 (fragment-chunk order, f16(64*mat))
    prep_mat<<<dim3(128), 256, 0, stream>>>(mat, MAT16);
    // P1: CH16 = f16(16*chart_h), grid-stride streaming convert
    conv_h<<<dim3(2048), 256, 0, stream>>>(chart_h, CH16);
    // K2': fused T-slice MFMA + cheap scores + top3 + candidate queue
    //      (Ts overlays Arh: LDS 34KB -> 4 blocks/CU)
    score_fused<<<dim3(B_DIM * L_DIM), 256, 0, stream>>>(chart_h, CH16, MAT16,
                                                         chart_s, ITEMS, RBASE,
                                                         CNT, FLAGS, X, out);
    // (MAT16/CH16 dead from here; WcT/H overlay CH16 region)
    transpose_wc<<<dim3(16, 8), 256, 0, stream>>>(Wc, WcT);
    // K3a: exact eval, block per item pair (mat shared within pair)
    refine_eval<<<dim3(1024), 256, 0, stream>>>(chart_h, chart_s, mat, ITEMS, CNT, EXVAL);
    // K3b: per-row exact top-2 + outputs + X
    refine_pick<<<dim3(B_DIM * L_DIM), 256, 0, stream>>>(chart_h, ITEMS, RBASE, FLAGS,
                                                         EXVAL, X, out);
    // K4: H = tanh(X @ WcT^T + bc)
    gemm_compose<<<dim3(24, 4), 256, 0, stream>>>(X, WcT, bc, H, 3072, 512, 1024);
    // K5: topk_h = H / ||H||
    norm_rows<<<dim3(3072), 256, 0, stream>>>(H, out);
}